// Round 7
// baseline (113.240 us; speedup 1.0000x reference)
//
#include <hip/hip_runtime.h>
#include <hip/hip_bf16.h>
#include <math.h>

// B=4, T=128, S=512, D=512. Outputs: attn_h (4,128,512) then align (4,128,512), fp32.
// 5-kernel pipeline (R12 = R11 + global_load_lds GEMM staging):
//   K0 cvt_bf16 (1152): inp/ctx/Wq/Wc/Wout -> bf16 once
//   K1 fused_front (640): Ew=exp(2(inp@Wq^T+bq)), Eu=exp(2 ctx@Wc^T),
//      GT[b]=(WL@ctx_b^T) bf16, Y0=inp@WR^T+bout   (all operands bf16)
//   K2 align (2048): E = exp(V - 2*sum_d v[d]/(1+Ew*Eu)); halving-butterfly tail
//   K3 normalize (512): rowsum + alignv=E/s (fp32) + P_bf=bf16(E/s)
//   K4 gemm_att (64): attn = P_bf @ GT^T + Y0 (MFMA, K=512)
// gemm_body staging: global_load_lds dwordx4 (no VGPR round-trip), double-
// buffered LDS [2][64][64] linear + XOR chunk swizzle on BOTH sides (T21):
// source chunk = (l&7)^(row&7), read chunk = (quad+kk/8)^(row&7). One barrier
// per K-step (its vmcnt/lgkm drain doubles as the stage-completion wait).

typedef __attribute__((ext_vector_type(8))) short short8;
typedef __attribute__((ext_vector_type(4))) float f32x4;
typedef unsigned short ushort_t;

static __device__ __forceinline__ unsigned short f2bf(float x) {
    union { __hip_bfloat16 h; unsigned short u; } c;
    c.h = __float2bfloat16(x);
    return c.u;
}
static __device__ __forceinline__ int bf2x(float lo, float hi) {
    return (int)(((unsigned)f2bf(hi) << 16) | (unsigned)f2bf(lo));
}

// async global -> LDS, 16 bytes per lane (lds dest = wave-uniform base + lane*16)
static __device__ __forceinline__ void gld16(const ushort_t* g, ushort_t* l) {
    __builtin_amdgcn_global_load_lds(
        (const __attribute__((address_space(1))) unsigned int*)g,
        (__attribute__((address_space(3))) unsigned int*)l, 16, 0, 0);
}

// ---------------------------------------------------------------------------
// MFMA NT GEMM tile: C[m,n] = sum_k A[m,k]*W[n,k] (+bias). A,W bf16.
// 64x64 tile, BK=64, 256 thr = 4 waves (2x2 of 32x32), 2x2 MFMA 16x16x32.
// Staging: 4x global_load_lds_dwordx4 per thread per K-step into [2][4096]
// double buffer; XOR chunk swizzle keeps b128 reads <=2-way bank-aliased.
// EPI: 0 fp32+bias; 1 fp32 exp(2*(x+bias)); 2 bf16; 3 fp32 + partial[].
// ---------------------------------------------------------------------------
template<int EPI>
static __device__ __forceinline__ void gemm_body(
    ushort_t* As, ushort_t* Ws,          // each [2*4096]
    const ushort_t* A, const ushort_t* W,
    const float* bias, const float* partial,
    void* Cv, int K, int lda, int ldw, int ldc, int bm, int bn)
{
    const int tid = threadIdx.x;
    const int wave = tid >> 6, lane = tid & 63;
    const int mh = (wave & 1) * 32, nh = (wave >> 1) * 32;
    const int quad = lane >> 4, l16 = lane & 15;

    // staging geometry: wave `wave`, lane `lane` covers
    //   issue0: row sr0 = 8*wave + (lane>>3), issue1: row sr0+32
    //   LDS slot chunk = lane&7  ->  global chunk = (lane&7) ^ (row&7)
    const int sr0 = 8 * wave + (lane >> 3);
    const int sc  = (((lane & 7) ^ (sr0 & 7)) << 3);   // element offset (16B chunk)
    const size_t ga0 = (size_t)(bm + sr0) * lda + sc;
    const size_t ga1 = (size_t)(bm + sr0 + 32) * lda + sc;
    const size_t gw0 = (size_t)(bn + sr0) * ldw + sc;
    const size_t gw1 = (size_t)(bn + sr0 + 32) * ldw + sc;
    ushort_t* al0 = As + wave * 512;          // wave-uniform LDS bases
    ushort_t* al1 = As + 2048 + wave * 512;
    ushort_t* wl0 = Ws + wave * 512;
    ushort_t* wl1 = Ws + 2048 + wave * 512;

    f32x4 acc00 = {0.f, 0.f, 0.f, 0.f}, acc01 = acc00, acc10 = acc00, acc11 = acc00;

    // prologue: stage k0=0 into buffer 0
    gld16(A + ga0, al0);
    gld16(A + ga1, al1);
    gld16(W + gw0, wl0);
    gld16(W + gw1, wl1);

    const int swz = l16 & 7;
    int cur = 0;
    for (int k0 = 0; k0 < K; k0 += 64) {
        __syncthreads();                      // drains vmcnt -> buf[cur] ready
        if (k0 + 64 < K) {
            const int nb = (cur ^ 1) * 4096;
            gld16(A + ga0 + k0 + 64, al0 + nb);
            gld16(A + ga1 + k0 + 64, al1 + nb);
            gld16(W + gw0 + k0 + 64, wl0 + nb);
            gld16(W + gw1 + k0 + 64, wl1 + nb);
        }
        const ushort_t* Ab = As + cur * 4096;
        const ushort_t* Wb = Ws + cur * 4096;
        #pragma unroll
        for (int kc = 0; kc < 8; kc += 4) {   // kc = kk/8 for kk = 0,32
            const int ch = ((quad + kc) ^ swz) << 3;
            short8 a0 = *(const short8*)&Ab[(mh + l16) * 64 + ch];
            short8 a1 = *(const short8*)&Ab[(mh + 16 + l16) * 64 + ch];
            short8 b0 = *(const short8*)&Wb[(nh + l16) * 64 + ch];
            short8 b1 = *(const short8*)&Wb[(nh + 16 + l16) * 64 + ch];
            acc00 = __builtin_amdgcn_mfma_f32_16x16x32_bf16(a0, b0, acc00, 0, 0, 0);
            acc01 = __builtin_amdgcn_mfma_f32_16x16x32_bf16(a0, b1, acc01, 0, 0, 0);
            acc10 = __builtin_amdgcn_mfma_f32_16x16x32_bf16(a1, b0, acc10, 0, 0, 0);
            acc11 = __builtin_amdgcn_mfma_f32_16x16x32_bf16(a1, b1, acc11, 0, 0, 0);
        }
        cur ^= 1;
    }

    const int col0 = bn + nh + l16;
    const int col1 = col0 + 16;
    float bias0 = bias ? bias[col0] : 0.f;
    float bias1 = bias ? bias[col1] : 0.f;

    f32x4 accs[2][2] = {{acc00, acc01}, {acc10, acc11}};
    #pragma unroll
    for (int mt = 0; mt < 2; ++mt) {
        #pragma unroll
        for (int r = 0; r < 4; ++r) {
            int row = bm + mh + mt * 16 + quad * 4 + r;
            size_t rowoff = (size_t)row * ldc;
            float v0 = accs[mt][0][r] + bias0;
            float v1 = accs[mt][1][r] + bias1;
            if (EPI == 1) { v0 = __expf(2.f * v0); v1 = __expf(2.f * v1); }
            if (EPI == 3) { v0 += partial[rowoff + col0]; v1 += partial[rowoff + col1]; }
            if (EPI == 2) {
                ushort_t* C = (ushort_t*)Cv;
                C[rowoff + col0] = f2bf(v0);
                C[rowoff + col1] = f2bf(v1);
            } else {
                float* C = (float*)Cv;
                C[rowoff + col0] = v0;
                C[rowoff + col1] = v1;
            }
        }
    }
}

// ---------------------------------------------------------------------------
// K0: fp32 -> bf16 pre-convert. 2048 elems/block (256 thr x 8).
// [0,128) inp | [128,640) ctx | [640,768) Wq | [768,896) Wc | [896,1152) Wout
// ---------------------------------------------------------------------------
__global__ __launch_bounds__(256) void cvt_bf16(
    const float* __restrict__ inp, const float* __restrict__ ctx,
    const float* __restrict__ Wq, const float* __restrict__ Wc,
    const float* __restrict__ Wout,
    ushort_t* __restrict__ inpb, ushort_t* __restrict__ ctxb,
    ushort_t* __restrict__ Wqb, ushort_t* __restrict__ Wcb,
    ushort_t* __restrict__ Woutb)
{
    const int bid = blockIdx.x;
    const float* src; ushort_t* dst; int base;
    if (bid < 128)      { src = inp;  dst = inpb;  base = bid; }
    else if (bid < 640) { src = ctx;  dst = ctxb;  base = bid - 128; }
    else if (bid < 768) { src = Wq;   dst = Wqb;   base = bid - 640; }
    else if (bid < 896) { src = Wc;   dst = Wcb;   base = bid - 768; }
    else                { src = Wout; dst = Woutb; base = bid - 896; }
    const size_t off = (size_t)base * 2048 + (size_t)threadIdx.x * 8;
    const float4* s = (const float4*)(src + off);
    float4 a = s[0], b = s[1];
    int4 r;
    r.x = bf2x(a.x, a.y); r.y = bf2x(a.z, a.w);
    r.z = bf2x(b.x, b.y); r.w = bf2x(b.z, b.w);
    *(int4*)(dst + off) = r;
}

// ---------------------------------------------------------------------------
// K1: fused front (640 GEMM blocks), all operands bf16
// [0,64)    Ew = exp(2*(inp@Wq^T + bq))
// [64,320)  Eu = exp(2*(ctx@Wc^T))
// [320,576) GT[b][n,s] = sum_d WL[n,d]*ctx[b][s,d]  (bf16)
// [576,640) Y0 = inp@WR^T + bout
// ---------------------------------------------------------------------------
__global__ __launch_bounds__(256) void fused_front(
    const ushort_t* __restrict__ inpb, const ushort_t* __restrict__ ctxb,
    const ushort_t* __restrict__ Wqb, const float* __restrict__ bq,
    const ushort_t* __restrict__ Wcb, const ushort_t* __restrict__ Woutb,
    const float* __restrict__ bout,
    float* __restrict__ Ew, float* __restrict__ Eu, float* __restrict__ Y0,
    ushort_t* __restrict__ GT)
{
    __shared__ ushort_t As[2 * 4096];
    __shared__ ushort_t Ws[2 * 4096];
    const int bid = blockIdx.x;

    if (bid < 64) {
        gemm_body<1>(As, Ws, inpb, Wqb, bq, nullptr, Ew,
                     512, 512, 512, 512, (bid & 7) * 64, (bid >> 3) * 64);
    } else if (bid < 320) {
        int i = bid - 64;
        gemm_body<1>(As, Ws, ctxb, Wcb, nullptr, nullptr, Eu,
                     512, 512, 512, 512, (i & 31) * 64, (i >> 5) * 64);
    } else if (bid < 576) {
        int i = bid - 320;
        int b = i >> 6, j = i & 63;
        gemm_body<2>(As, Ws, Woutb, ctxb + (size_t)b * 262144, nullptr,
                     nullptr, GT + (size_t)b * 262144,
                     512, 1024, 512, 512, (j & 7) * 64, (j >> 3) * 64);
    } else {
        int i = bid - 576;
        gemm_body<0>(As, Ws, inpb, Woutb + 512, bout, nullptr, Y0,
                     512, 512, 1024, 512, (i & 7) * 64, (i >> 3) * 64);
    }
}

// ---------------------------------------------------------------------------
// K2: E[b,t,s] = exp(V - 2*sum_d v[d]/(1 + Ew[b,t,d]*Eu[b,s,d])),  V = sum v[d]
// Main loop: R7/R10 verbatim (k across lanes, paired rcp).
// Tail: multi-value halving butterfly (32 shuffles); exp applied here
// (maxless, fp32-safe since |S| <= sum|v| ~ 18).  [R11 verbatim]
// ---------------------------------------------------------------------------
__global__ __launch_bounds__(256) void align_kernel(
    const float* __restrict__ Ew, const float* __restrict__ Eu,
    const float* __restrict__ v, float* __restrict__ out)
{
    const int lane = threadIdx.x & 63, wave = threadIdx.x >> 6;
    const int b = blockIdx.z;
    const int t0 = blockIdx.y * 16 + wave * 4;
    const int s0 = blockIdx.x * 8;

    const float* wp = Ew + (((size_t)(b * 128 + t0)) << 9);
    const float* up = Eu + (((size_t)(b * 512 + s0)) << 9);

    float acc[4][8];
    #pragma unroll
    for (int i = 0; i < 4; ++i)
        #pragma unroll
        for (int j = 0; j < 8; ++j) acc[i][j] = 0.f;
    float vsum = 0.f;

    for (int k0 = 0; k0 < 512; k0 += 128) {
        float va = v[k0 + lane];
        float vb = v[k0 + 64 + lane];
        vsum += va + vb;
        float wa[4], wb[4];
        #pragma unroll
        for (int i = 0; i < 4; ++i) {
            wa[i] = wp[i * 512 + k0 + lane];
            wb[i] = wp[i * 512 + k0 + 64 + lane];
        }
        #pragma unroll
        for (int j = 0; j < 8; ++j) {
            const float* u = up + ((size_t)j << 9) + k0 + lane;
            float ua = u[0];
            float ub = u[64];
            #pragma unroll
            for (int i = 0; i < 4; ++i) {
                float A = fmaf(wa[i], ua, 1.f);
                float B = fmaf(wb[i], ub, 1.f);
                float num = fmaf(va, B, vb * A);
                float r = __builtin_amdgcn_rcpf(A * B);
                acc[i][j] = fmaf(num, r, acc[i][j]);
            }
        }
    }

    float V = vsum;
    #pragma unroll
    for (int off = 32; off; off >>= 1) V += __shfl_xor(V, off, 64);

    float x16[16];
    {
        const bool hb = lane & 1;
        #pragma unroll
        for (int i = 0; i < 4; ++i)
            #pragma unroll
            for (int m = 0; m < 4; ++m) {
                float keep = hb ? acc[i][2 * m + 1] : acc[i][2 * m];
                float send = hb ? acc[i][2 * m]     : acc[i][2 * m + 1];
                x16[i * 4 + m] = keep + __shfl_xor(send, 1, 64);
            }
    }
    float x8[8];
    {
        const bool hb = lane & 2;
        #pragma unroll
        for (int m = 0; m < 8; ++m) {
            float keep = hb ? x16[2 * m + 1] : x16[2 * m];
            float send = hb ? x16[2 * m]     : x16[2 * m + 1];
            x8[m] = keep + __shfl_xor(send, 2, 64);
        }
    }
    float x4[4];
    {
        const bool hb = lane & 4;
        #pragma unroll
        for (int m = 0; m < 4; ++m) {
            float keep = hb ? x8[2 * m + 1] : x8[2 * m];
            float send = hb ? x8[2 * m]     : x8[2 * m + 1];
            x4[m] = keep + __shfl_xor(send, 4, 64);
        }
    }
    float x2[2];
    {
        const bool hb = lane & 8;
        #pragma unroll
        for (int m = 0; m < 2; ++m) {
            float keep = hb ? x4[2 * m + 1] : x4[2 * m];
            float send = hb ? x4[2 * m]     : x4[2 * m + 1];
            x2[m] = keep + __shfl_xor(send, 8, 64);
        }
    }
    float x1;
    {
        const bool hb = lane & 16;
        float keep = hb ? x2[1] : x2[0];
        float send = hb ? x2[0] : x2[1];
        x1 = keep + __shfl_xor(send, 16, 64);
    }
    x1 += __shfl_xor(x1, 32, 64);

    const int oi = (lane >> 3) & 3;
    const int oj = lane & 7;
    float e = __expf(fmaf(-2.f, x1, V));
    if (lane < 32) {
        out[(((size_t)(b * 128 + t0 + oi)) << 9) + s0 + oj] = e;
    }
}

// ---------------------------------------------------------------------------
// K3: maxless normalize over rows of 512. Reads E=exp(S), writes fp32 alignv
// (=E/rowsum) + bf16 P.  [R11 verbatim]
// ---------------------------------------------------------------------------
__global__ __launch_bounds__(256) void normalize_512(
    const float* __restrict__ E, float* __restrict__ alignv,
    ushort_t* __restrict__ pbf)
{
    const int row = blockIdx.x;
    const float* p = E + ((size_t)row << 9);
    float* a = alignv + ((size_t)row << 9);
    ushort_t* q = pbf + ((size_t)row << 9);
    const int tid = threadIdx.x;
    float e0 = p[tid];
    float e1 = p[tid + 256];

    float s = e0 + e1;
    #pragma unroll
    for (int off = 32; off > 0; off >>= 1)
        s += __shfl_xor(s, off, 64);
    __shared__ float reds[4];
    const int wave = tid >> 6;
    if ((tid & 63) == 0) reds[wave] = s;
    __syncthreads();
    s = (reds[0] + reds[1]) + (reds[2] + reds[3]);
    float r = 1.0f / s;
    float p0 = e0 * r, p1 = e1 * r;
    a[tid] = p0;
    a[tid + 256] = p1;
    q[tid] = f2bf(p0);
    q[tid + 256] = f2bf(p1);
}

// ---------------------------------------------------------------------------
// K4: attn = P_bf @ GT^T + Y0. Per-batch M=128, N=512, K=512. Grid (2,8,4).
// ---------------------------------------------------------------------------
__global__ __launch_bounds__(256) void gemm_att(
    const ushort_t* __restrict__ P, const ushort_t* __restrict__ GT,
    const float* __restrict__ Y0, float* __restrict__ attn)
{
    __shared__ ushort_t As[2 * 4096];
    __shared__ ushort_t Ws[2 * 4096];
    const int b = blockIdx.z;
    gemm_body<3>(As, Ws,
                 P + (size_t)b * 65536, GT + (size_t)b * 262144,
                 nullptr, Y0 + (size_t)b * 65536,
                 attn + (size_t)b * 65536,
                 512, 512, 512, 512, blockIdx.x * 64, blockIdx.y * 64);
}

// ---------------------------------------------------------------------------
extern "C" void kernel_launch(void* const* d_in, const int* in_sizes, int n_in,
                              void* d_out, int out_size, void* d_ws, size_t ws_size,
                              hipStream_t stream)
{
    const float* inp  = (const float*)d_in[0];   // (4,128,512)
    const float* ctx  = (const float*)d_in[1];   // (4,512,512)
    const float* Wq   = (const float*)d_in[2];   // (512,512)
    const float* bq   = (const float*)d_in[3];   // (512)
    const float* Wc   = (const float*)d_in[4];   // (512,512)
    const float* v    = (const float*)d_in[5];   // (512)
    const float* Wout = (const float*)d_in[6];   // (512,1024)
    const float* bout = (const float*)d_in[7];   // (512)

    float* out    = (float*)d_out;
    float* attn   = out;              // 262144 floats
    float* alignv = out + 262144;     // 262144 floats

    float* ws = (float*)d_ws;
    float* Ew   = ws;                             // 262144 f
    float* Eu   = ws + 262144;                    // 1048576 f
    float* Y0   = ws + 1310720;                   // 262144 f
    float* E    = ws + 1572864;                   // 262144 f (exp of raw scores)
    ushort_t* GT   = (ushort_t*)(ws + 1835008);   // 1048576 u16 (= 524288 f)
    ushort_t* P_bf = (ushort_t*)(ws + 2359296);   // 262144 u16 (= 131072 f)
    ushort_t* inpb  = (ushort_t*)(ws + 2490368);  // 262144 u16
    ushort_t* ctxb  = (ushort_t*)(ws + 2621440);  // 1048576 u16
    ushort_t* Wqb   = (ushort_t*)(ws + 3145728);  // 262144 u16
    ushort_t* Wcb   = (ushort_t*)(ws + 3276800);  // 262144 u16
    ushort_t* Woutb = (ushort_t*)(ws + 3407872);  // 524288 u16

    cvt_bf16<<<dim3(1152), 256, 0, stream>>>(inp, ctx, Wq, Wc, Wout,
                                             inpb, ctxb, Wqb, Wcb, Woutb);
    fused_front<<<dim3(640), 256, 0, stream>>>(inpb, ctxb, Wqb, bq, Wcb, Woutb,
                                               bout, Ew, Eu, Y0, GT);
    align_kernel<<<dim3(64, 8, 4), 256, 0, stream>>>(Ew, Eu, v, E);
    normalize_512<<<dim3(512), 256, 0, stream>>>(E, alignv, P_bf);
    gemm_att<<<dim3(2, 8, 4), 256, 0, stream>>>(P_bf, GT, Y0, attn);
}

// Round 8
// 110.319 us; speedup vs baseline: 1.0265x; 1.0265x over previous
//
#include <hip/hip_runtime.h>
#include <hip/hip_bf16.h>
#include <math.h>

// B=4, T=128, S=512, D=512. Outputs: attn_h (4,128,512) then align (4,128,512), fp32.
// 5-kernel pipeline (R13 = R11 verbatim + K=512 hardcoded, K-loop fully unrolled):
//   K0 cvt_bf16 (1152): inp/ctx/Wq/Wc/Wout -> bf16 once
//   K1 fused_front (640): Ew=exp(2(inp@Wq^T+bq)), Eu=exp(2 ctx@Wc^T),
//      GT[b]=(WL@ctx_b^T) bf16, Y0=inp@WR^T+bout   (all operands bf16)
//   K2 align (2048): E = exp(V - 2*sum_d v[d]/(1+Ew*Eu)); paired rcp;
//      halving-butterfly tail (32 shuffles); maxless exp (|S|<=18, fp32-safe)
//   K3 normalize (512): rowsum + alignv=E/s (fp32) + P_bf=bf16(E/s)
//   K4 gemm_att (64): attn = P_bf @ GT^T + Y0 (MFMA, K=512)
// NOTE (R12 lesson): global_load_lds+dbuf REGRESSED here (+2.9us) -- at 64^2
// tile only 8 MFMA/phase (~80cy) cannot cover ~300cy load latency that the
// barrier must drain. Reg-staged (load->VGPR early, ds_write late) wins at
// this tile size. Do not re-attempt without a bigger tile.

typedef __attribute__((ext_vector_type(8))) short short8;
typedef __attribute__((ext_vector_type(4))) float f32x4;
typedef unsigned short ushort_t;

static __device__ __forceinline__ unsigned short f2bf(float x) {
    union { __hip_bfloat16 h; unsigned short u; } c;
    c.h = __float2bfloat16(x);
    return c.u;
}
static __device__ __forceinline__ int bf2x(float lo, float hi) {
    return (int)(((unsigned)f2bf(hi) << 16) | (unsigned)f2bf(lo));
}

template<bool BF>
static __device__ __forceinline__ void load16(const void* base, size_t elemoff,
                                              int4& r0, int4& r1) {
    if (BF) {
        const int4* p = (const int4*)((const ushort_t*)base + elemoff);
        r0 = p[0]; r1 = p[1];
    } else {
        const float4* p = (const float4*)((const float*)base + elemoff);
        float4 a = p[0], b = p[1], c = p[2], d = p[3];
        r0.x = bf2x(a.x, a.y); r0.y = bf2x(a.z, a.w);
        r0.z = bf2x(b.x, b.y); r0.w = bf2x(b.z, b.w);
        r1.x = bf2x(c.x, c.y); r1.y = bf2x(c.z, c.w);
        r1.z = bf2x(d.x, d.y); r1.w = bf2x(d.z, d.w);
    }
}

// ---------------------------------------------------------------------------
// MFMA NT GEMM tile: C[m,n] = sum_k A[m,k]*W[n,k] (+bias). K=512 fixed.
// 64x64 tile, BK=64, 256 thr = 4 waves (2x2 of 32x32), 2x2 MFMA 16x16x32.
// LDS rows padded to 72 bf16 (<=2-way bank aliasing on b128 = free).
// K-loop fully unrolled (8 iters): branch-free staging, cross-iter scheduling.
// EPI: 0 fp32+bias; 1 fp32 exp(2*(x+bias)); 2 bf16; 3 fp32 + partial[].
// ---------------------------------------------------------------------------
template<bool A_BF, bool W_BF, int EPI>
static __device__ __forceinline__ void gemm_body(
    ushort_t* As, ushort_t* Ws,
    const void* A, const void* W, const float* bias, const float* partial,
    void* Cv, int lda, int ldw, int ldc, int bm, int bn)
{
    const int tid = threadIdx.x;
    const int wave = tid >> 6, lane = tid & 63;
    const int mh = (wave & 1) * 32, nh = (wave >> 1) * 32;
    const int quad = lane >> 4, l16 = lane & 15;
    const int srow = tid >> 2, schunk = tid & 3;

    const size_t aoff = (size_t)(bm + srow) * lda + schunk * 16;
    const size_t woff = (size_t)(bn + srow) * ldw + schunk * 16;
    int4* AsW = (int4*)&As[srow * 72 + schunk * 16];
    int4* WsW = (int4*)&Ws[srow * 72 + schunk * 16];

    f32x4 acc00 = {0.f, 0.f, 0.f, 0.f}, acc01 = acc00, acc10 = acc00, acc11 = acc00;

    int4 a0r, a1r, w0r, w1r;
    load16<A_BF>(A, aoff, a0r, a1r);
    load16<W_BF>(W, woff, w0r, w1r);

    #pragma unroll
    for (int k0 = 0; k0 < 512; k0 += 64) {
        AsW[0] = a0r; AsW[1] = a1r;
        WsW[0] = w0r; WsW[1] = w1r;
        __syncthreads();
        if (k0 + 64 < 512) {
            load16<A_BF>(A, aoff + k0 + 64, a0r, a1r);
            load16<W_BF>(W, woff + k0 + 64, w0r, w1r);
        }
        #pragma unroll
        for (int kk = 0; kk < 64; kk += 32) {
            short8 a0 = *(const short8*)&As[(mh + l16) * 72 + kk + quad * 8];
            short8 a1 = *(const short8*)&As[(mh + 16 + l16) * 72 + kk + quad * 8];
            short8 b0 = *(const short8*)&Ws[(nh + l16) * 72 + kk + quad * 8];
            short8 b1 = *(const short8*)&Ws[(nh + 16 + l16) * 72 + kk + quad * 8];
            acc00 = __builtin_amdgcn_mfma_f32_16x16x32_bf16(a0, b0, acc00, 0, 0, 0);
            acc01 = __builtin_amdgcn_mfma_f32_16x16x32_bf16(a0, b1, acc01, 0, 0, 0);
            acc10 = __builtin_amdgcn_mfma_f32_16x16x32_bf16(a1, b0, acc10, 0, 0, 0);
            acc11 = __builtin_amdgcn_mfma_f32_16x16x32_bf16(a1, b1, acc11, 0, 0, 0);
        }
        __syncthreads();
    }

    const int col0 = bn + nh + l16;
    const int col1 = col0 + 16;
    float bias0 = bias ? bias[col0] : 0.f;
    float bias1 = bias ? bias[col1] : 0.f;

    f32x4 accs[2][2] = {{acc00, acc01}, {acc10, acc11}};
    #pragma unroll
    for (int mt = 0; mt < 2; ++mt) {
        #pragma unroll
        for (int r = 0; r < 4; ++r) {
            int row = bm + mh + mt * 16 + quad * 4 + r;
            size_t rowoff = (size_t)row * ldc;
            float v0 = accs[mt][0][r] + bias0;
            float v1 = accs[mt][1][r] + bias1;
            if (EPI == 1) { v0 = __expf(2.f * v0); v1 = __expf(2.f * v1); }
            if (EPI == 3) { v0 += partial[rowoff + col0]; v1 += partial[rowoff + col1]; }
            if (EPI == 2) {
                ushort_t* C = (ushort_t*)Cv;
                C[rowoff + col0] = f2bf(v0);
                C[rowoff + col1] = f2bf(v1);
            } else {
                float* C = (float*)Cv;
                C[rowoff + col0] = v0;
                C[rowoff + col1] = v1;
            }
        }
    }
}

// ---------------------------------------------------------------------------
// K0: fp32 -> bf16 pre-convert. 2048 elems/block (256 thr x 8).
// [0,128) inp | [128,640) ctx | [640,768) Wq | [768,896) Wc | [896,1152) Wout
// ---------------------------------------------------------------------------
__global__ __launch_bounds__(256) void cvt_bf16(
    const float* __restrict__ inp, const float* __restrict__ ctx,
    const float* __restrict__ Wq, const float* __restrict__ Wc,
    const float* __restrict__ Wout,
    ushort_t* __restrict__ inpb, ushort_t* __restrict__ ctxb,
    ushort_t* __restrict__ Wqb, ushort_t* __restrict__ Wcb,
    ushort_t* __restrict__ Woutb)
{
    const int bid = blockIdx.x;
    const float* src; ushort_t* dst; int base;
    if (bid < 128)      { src = inp;  dst = inpb;  base = bid; }
    else if (bid < 640) { src = ctx;  dst = ctxb;  base = bid - 128; }
    else if (bid < 768) { src = Wq;   dst = Wqb;   base = bid - 640; }
    else if (bid < 896) { src = Wc;   dst = Wcb;   base = bid - 768; }
    else                { src = Wout; dst = Woutb; base = bid - 896; }
    const size_t off = (size_t)base * 2048 + (size_t)threadIdx.x * 8;
    const float4* s = (const float4*)(src + off);
    float4 a = s[0], b = s[1];
    int4 r;
    r.x = bf2x(a.x, a.y); r.y = bf2x(a.z, a.w);
    r.z = bf2x(b.x, b.y); r.w = bf2x(b.z, b.w);
    *(int4*)(dst + off) = r;
}

// ---------------------------------------------------------------------------
// K1: fused front (640 GEMM blocks), all operands bf16
// [0,64)    Ew = exp(2*(inp@Wq^T + bq))
// [64,320)  Eu = exp(2*(ctx@Wc^T))
// [320,576) GT[b][n,s] = sum_d WL[n,d]*ctx[b][s,d]  (bf16)
// [576,640) Y0 = inp@WR^T + bout
// ---------------------------------------------------------------------------
__global__ __launch_bounds__(256) void fused_front(
    const ushort_t* __restrict__ inpb, const ushort_t* __restrict__ ctxb,
    const ushort_t* __restrict__ Wqb, const float* __restrict__ bq,
    const ushort_t* __restrict__ Wcb, const ushort_t* __restrict__ Woutb,
    const float* __restrict__ bout,
    float* __restrict__ Ew, float* __restrict__ Eu, float* __restrict__ Y0,
    ushort_t* __restrict__ GT)
{
    __shared__ ushort_t As[64 * 72];
    __shared__ ushort_t Ws[64 * 72];
    const int bid = blockIdx.x;

    if (bid < 64) {
        gemm_body<true, true, 1>(As, Ws, inpb, Wqb, bq, nullptr, Ew,
                                 512, 512, 512, (bid & 7) * 64, (bid >> 3) * 64);
    } else if (bid < 320) {
        int i = bid - 64;
        gemm_body<true, true, 1>(As, Ws, ctxb, Wcb, nullptr, nullptr, Eu,
                                 512, 512, 512, (i & 31) * 64, (i >> 5) * 64);
    } else if (bid < 576) {
        int i = bid - 320;
        int b = i >> 6, j = i & 63;
        gemm_body<true, true, 2>(As, Ws, Woutb, ctxb + (size_t)b * 262144, nullptr,
                                 nullptr, GT + (size_t)b * 262144,
                                 1024, 512, 512, (j & 7) * 64, (j >> 3) * 64);
    } else {
        int i = bid - 576;
        gemm_body<true, true, 0>(As, Ws, inpb, Woutb + 512, bout, nullptr, Y0,
                                 512, 1024, 512, (i & 7) * 64, (i >> 3) * 64);
    }
}

// ---------------------------------------------------------------------------
// K2: E[b,t,s] = exp(V - 2*sum_d v[d]/(1 + Ew[b,t,d]*Eu[b,s,d])),  V = sum v[d]
// Main loop: k across lanes, paired rcp (1 rcp / 2 d-elems).
// Tail: multi-value halving butterfly (32 shuffles); maxless exp. [R11 verbatim]
// ---------------------------------------------------------------------------
__global__ __launch_bounds__(256) void align_kernel(
    const float* __restrict__ Ew, const float* __restrict__ Eu,
    const float* __restrict__ v, float* __restrict__ out)
{
    const int lane = threadIdx.x & 63, wave = threadIdx.x >> 6;
    const int b = blockIdx.z;
    const int t0 = blockIdx.y * 16 + wave * 4;
    const int s0 = blockIdx.x * 8;

    const float* wp = Ew + (((size_t)(b * 128 + t0)) << 9);
    const float* up = Eu + (((size_t)(b * 512 + s0)) << 9);

    float acc[4][8];
    #pragma unroll
    for (int i = 0; i < 4; ++i)
        #pragma unroll
        for (int j = 0; j < 8; ++j) acc[i][j] = 0.f;
    float vsum = 0.f;

    for (int k0 = 0; k0 < 512; k0 += 128) {
        float va = v[k0 + lane];
        float vb = v[k0 + 64 + lane];
        vsum += va + vb;
        float wa[4], wb[4];
        #pragma unroll
        for (int i = 0; i < 4; ++i) {
            wa[i] = wp[i * 512 + k0 + lane];
            wb[i] = wp[i * 512 + k0 + 64 + lane];
        }
        #pragma unroll
        for (int j = 0; j < 8; ++j) {
            const float* u = up + ((size_t)j << 9) + k0 + lane;
            float ua = u[0];
            float ub = u[64];
            #pragma unroll
            for (int i = 0; i < 4; ++i) {
                float A = fmaf(wa[i], ua, 1.f);
                float B = fmaf(wb[i], ub, 1.f);
                float num = fmaf(va, B, vb * A);
                float r = __builtin_amdgcn_rcpf(A * B);
                acc[i][j] = fmaf(num, r, acc[i][j]);
            }
        }
    }

    float V = vsum;
    #pragma unroll
    for (int off = 32; off; off >>= 1) V += __shfl_xor(V, off, 64);

    float x16[16];
    {
        const bool hb = lane & 1;
        #pragma unroll
        for (int i = 0; i < 4; ++i)
            #pragma unroll
            for (int m = 0; m < 4; ++m) {
                float keep = hb ? acc[i][2 * m + 1] : acc[i][2 * m];
                float send = hb ? acc[i][2 * m]     : acc[i][2 * m + 1];
                x16[i * 4 + m] = keep + __shfl_xor(send, 1, 64);
            }
    }
    float x8[8];
    {
        const bool hb = lane & 2;
        #pragma unroll
        for (int m = 0; m < 8; ++m) {
            float keep = hb ? x16[2 * m + 1] : x16[2 * m];
            float send = hb ? x16[2 * m]     : x16[2 * m + 1];
            x8[m] = keep + __shfl_xor(send, 2, 64);
        }
    }
    float x4[4];
    {
        const bool hb = lane & 4;
        #pragma unroll
        for (int m = 0; m < 4; ++m) {
            float keep = hb ? x8[2 * m + 1] : x8[2 * m];
            float send = hb ? x8[2 * m]     : x8[2 * m + 1];
            x4[m] = keep + __shfl_xor(send, 4, 64);
        }
    }
    float x2[2];
    {
        const bool hb = lane & 8;
        #pragma unroll
        for (int m = 0; m < 2; ++m) {
            float keep = hb ? x4[2 * m + 1] : x4[2 * m];
            float send = hb ? x4[2 * m]     : x4[2 * m + 1];
            x2[m] = keep + __shfl_xor(send, 8, 64);
        }
    }
    float x1;
    {
        const bool hb = lane & 16;
        float keep = hb ? x2[1] : x2[0];
        float send = hb ? x2[0] : x2[1];
        x1 = keep + __shfl_xor(send, 16, 64);
    }
    x1 += __shfl_xor(x1, 32, 64);

    const int oi = (lane >> 3) & 3;
    const int oj = lane & 7;
    float e = __expf(fmaf(-2.f, x1, V));
    if (lane < 32) {
        out[(((size_t)(b * 128 + t0 + oi)) << 9) + s0 + oj] = e;
    }
}

// ---------------------------------------------------------------------------
// K3: maxless normalize over rows of 512. Reads E=exp(S), writes fp32 alignv
// (=E/rowsum) + bf16 P.  [R11 verbatim]
// ---------------------------------------------------------------------------
__global__ __launch_bounds__(256) void normalize_512(
    const float* __restrict__ E, float* __restrict__ alignv,
    ushort_t* __restrict__ pbf)
{
    const int row = blockIdx.x;
    const float* p = E + ((size_t)row << 9);
    float* a = alignv + ((size_t)row << 9);
    ushort_t* q = pbf + ((size_t)row << 9);
    const int tid = threadIdx.x;
    float e0 = p[tid];
    float e1 = p[tid + 256];

    float s = e0 + e1;
    #pragma unroll
    for (int off = 32; off > 0; off >>= 1)
        s += __shfl_xor(s, off, 64);
    __shared__ float reds[4];
    const int wave = tid >> 6;
    if ((tid & 63) == 0) reds[wave] = s;
    __syncthreads();
    s = (reds[0] + reds[1]) + (reds[2] + reds[3]);
    float r = 1.0f / s;
    float p0 = e0 * r, p1 = e1 * r;
    a[tid] = p0;
    a[tid + 256] = p1;
    q[tid] = f2bf(p0);
    q[tid + 256] = f2bf(p1);
}

// ---------------------------------------------------------------------------
// K4: attn = P_bf @ GT^T + Y0. Per-batch M=128, N=512, K=512. Grid (2,8,4).
// ---------------------------------------------------------------------------
__global__ __launch_bounds__(256) void gemm_att(
    const ushort_t* __restrict__ P, const ushort_t* __restrict__ GT,
    const float* __restrict__ Y0, float* __restrict__ attn)
{
    __shared__ ushort_t As[64 * 72];
    __shared__ ushort_t Ws[64 * 72];
    const int b = blockIdx.z;
    gemm_body<true, true, 3>(As, Ws,
                             P + (size_t)b * 65536, GT + (size_t)b * 262144,
                             nullptr, Y0 + (size_t)b * 65536,
                             attn + (size_t)b * 65536,
                             512, 512, 512, blockIdx.x * 64, blockIdx.y * 64);
}

// ---------------------------------------------------------------------------
extern "C" void kernel_launch(void* const* d_in, const int* in_sizes, int n_in,
                              void* d_out, int out_size, void* d_ws, size_t ws_size,
                              hipStream_t stream)
{
    const float* inp  = (const float*)d_in[0];   // (4,128,512)
    const float* ctx  = (const float*)d_in[1];   // (4,512,512)
    const float* Wq   = (const float*)d_in[2];   // (512,512)
    const float* bq   = (const float*)d_in[3];   // (512)
    const float* Wc   = (const float*)d_in[4];   // (512,512)
    const float* v    = (const float*)d_in[5];   // (512)
    const float* Wout = (const float*)d_in[6];   // (512,1024)
    const float* bout = (const float*)d_in[7];   // (512)

    float* out    = (float*)d_out;
    float* attn   = out;              // 262144 floats
    float* alignv = out + 262144;     // 262144 floats

    float* ws = (float*)d_ws;
    float* Ew   = ws;                             // 262144 f
    float* Eu   = ws + 262144;                    // 1048576 f
    float* Y0   = ws + 1310720;                   // 262144 f
    float* E    = ws + 1572864;                   // 262144 f (exp of raw scores)
    ushort_t* GT   = (ushort_t*)(ws + 1835008);   // 1048576 u16 (= 524288 f)
    ushort_t* P_bf = (ushort_t*)(ws + 2359296);   // 262144 u16 (= 131072 f)
    ushort_t* inpb  = (ushort_t*)(ws + 2490368);  // 262144 u16
    ushort_t* ctxb  = (ushort_t*)(ws + 2621440);  // 1048576 u16
    ushort_t* Wqb   = (ushort_t*)(ws + 3145728);  // 262144 u16
    ushort_t* Wcb   = (ushort_t*)(ws + 3276800);  // 262144 u16
    ushort_t* Woutb = (ushort_t*)(ws + 3407872);  // 524288 u16

    cvt_bf16<<<dim3(1152), 256, 0, stream>>>(inp, ctx, Wq, Wc, Wout,
                                             inpb, ctxb, Wqb, Wcb, Woutb);
    fused_front<<<dim3(640), 256, 0, stream>>>(inpb, ctxb, Wqb, bq, Wcb, Woutb,
                                               bout, Ew, Eu, Y0, GT);
    align_kernel<<<dim3(64, 8, 4), 256, 0, stream>>>(Ew, Eu, v, E);
    normalize_512<<<dim3(512), 256, 0, stream>>>(E, alignv, P_bf);
    gemm_att<<<dim3(2, 8, 4), 256, 0, stream>>>(P_bf, GT, Y0, attn);
}

// Round 9
// 109.986 us; speedup vs baseline: 1.0296x; 1.0030x over previous
//
#include <hip/hip_runtime.h>
#include <hip/hip_bf16.h>
#include <math.h>

// B=4, T=128, S=512, D=512. Outputs: attn_h (4,128,512) then align (4,128,512), fp32.
// 5-kernel pipeline (R14 = R13 + LDS double-buffer, ONE barrier per K-step):
//   K0 cvt_bf16 (1152): inp/ctx/Wq/Wc/Wout -> bf16 once
//   K1 fused_front (640): Ew=exp(2(inp@Wq^T+bq)), Eu=exp(2 ctx@Wc^T),
//      GT[b]=(WL@ctx_b^T) bf16, Y0=inp@WR^T+bout   (all operands bf16)
//   K2 align (2048): E = exp(V - 2*sum_d v[d]/(1+Ew*Eu)); paired rcp;
//      halving-butterfly tail (32 shuffles); maxless exp (|S|<=18, fp32-safe)
//   K3 normalize (512): rowsum + alignv=E/s (fp32) + P_bf=bf16(E/s)
//   K4 gemm_att (64): attn = P_bf @ GT^T + Y0 (MFMA, K=512)
// gemm_body: reg-staged (R12 lesson: global_load_lds regressed -- its vmcnt
// drain at the barrier exposes load latency at 64^2 tiles) + double-buffered
// LDS so each K-step needs ONE barrier (iteration i's barrier orders i-1
// reads of buf^1 before i+1's write of buf^1 -- race-free). 16 -> 8 barriers.

typedef __attribute__((ext_vector_type(8))) short short8;
typedef __attribute__((ext_vector_type(4))) float f32x4;
typedef unsigned short ushort_t;

static __device__ __forceinline__ unsigned short f2bf(float x) {
    union { __hip_bfloat16 h; unsigned short u; } c;
    c.h = __float2bfloat16(x);
    return c.u;
}
static __device__ __forceinline__ int bf2x(float lo, float hi) {
    return (int)(((unsigned)f2bf(hi) << 16) | (unsigned)f2bf(lo));
}

template<bool BF>
static __device__ __forceinline__ void load16(const void* base, size_t elemoff,
                                              int4& r0, int4& r1) {
    if (BF) {
        const int4* p = (const int4*)((const ushort_t*)base + elemoff);
        r0 = p[0]; r1 = p[1];
    } else {
        const float4* p = (const float4*)((const float*)base + elemoff);
        float4 a = p[0], b = p[1], c = p[2], d = p[3];
        r0.x = bf2x(a.x, a.y); r0.y = bf2x(a.z, a.w);
        r0.z = bf2x(b.x, b.y); r0.w = bf2x(b.z, b.w);
        r1.x = bf2x(c.x, c.y); r1.y = bf2x(c.z, c.w);
        r1.z = bf2x(d.x, d.y); r1.w = bf2x(d.z, d.w);
    }
}

// ---------------------------------------------------------------------------
// MFMA NT GEMM tile: C[m,n] = sum_k A[m,k]*W[n,k] (+bias). K=512 fixed.
// 64x64 tile, BK=64, 256 thr = 4 waves (2x2 of 32x32), 2x2 MFMA 16x16x32.
// LDS rows padded to 72 bf16 (<=2-way bank aliasing on b128 = free).
// Double-buffered [2][64*72]; one __syncthreads per K-step; loads for step
// i+1 issued right after the barrier (whole MFMA phase to cover latency).
// EPI: 0 fp32+bias; 1 fp32 exp(2*(x+bias)); 2 bf16; 3 fp32 + partial[].
// ---------------------------------------------------------------------------
template<bool A_BF, bool W_BF, int EPI>
static __device__ __forceinline__ void gemm_body(
    ushort_t* As, ushort_t* Ws,          // each [2*4608]
    const void* A, const void* W, const float* bias, const float* partial,
    void* Cv, int lda, int ldw, int ldc, int bm, int bn)
{
    const int tid = threadIdx.x;
    const int wave = tid >> 6, lane = tid & 63;
    const int mh = (wave & 1) * 32, nh = (wave >> 1) * 32;
    const int quad = lane >> 4, l16 = lane & 15;
    const int srow = tid >> 2, schunk = tid & 3;

    const size_t aoff = (size_t)(bm + srow) * lda + schunk * 16;
    const size_t woff = (size_t)(bn + srow) * ldw + schunk * 16;
    const int swoff = srow * 72 + schunk * 16;

    f32x4 acc00 = {0.f, 0.f, 0.f, 0.f}, acc01 = acc00, acc10 = acc00, acc11 = acc00;

    int4 a0r, a1r, w0r, w1r;
    load16<A_BF>(A, aoff, a0r, a1r);
    load16<W_BF>(W, woff, w0r, w1r);

    #pragma unroll
    for (int i = 0; i < 8; ++i) {
        const int bb = (i & 1) * 4608;
        // publish step-i tile into buffer i&1 (vmcnt wait inserted by compiler)
        *(int4*)&As[bb + swoff] = a0r; *((int4*)&As[bb + swoff] + 1) = a1r;
        *(int4*)&Ws[bb + swoff] = w0r; *((int4*)&Ws[bb + swoff] + 1) = w1r;
        __syncthreads();
        if (i < 7) {                     // prefetch step i+1 into registers
            load16<A_BF>(A, aoff + (i + 1) * 64, a0r, a1r);
            load16<W_BF>(W, woff + (i + 1) * 64, w0r, w1r);
        }
        const ushort_t* Ab = As + bb;
        const ushort_t* Wb = Ws + bb;
        #pragma unroll
        for (int kk = 0; kk < 64; kk += 32) {
            short8 a0 = *(const short8*)&Ab[(mh + l16) * 72 + kk + quad * 8];
            short8 a1 = *(const short8*)&Ab[(mh + 16 + l16) * 72 + kk + quad * 8];
            short8 b0 = *(const short8*)&Wb[(nh + l16) * 72 + kk + quad * 8];
            short8 b1 = *(const short8*)&Wb[(nh + 16 + l16) * 72 + kk + quad * 8];
            acc00 = __builtin_amdgcn_mfma_f32_16x16x32_bf16(a0, b0, acc00, 0, 0, 0);
            acc01 = __builtin_amdgcn_mfma_f32_16x16x32_bf16(a0, b1, acc01, 0, 0, 0);
            acc10 = __builtin_amdgcn_mfma_f32_16x16x32_bf16(a1, b0, acc10, 0, 0, 0);
            acc11 = __builtin_amdgcn_mfma_f32_16x16x32_bf16(a1, b1, acc11, 0, 0, 0);
        }
        // no trailing barrier: next step writes the OTHER buffer; the next
        // iteration's barrier (reached only after every wave drained this
        // step's reads) orders reuse of this buffer two steps later.
    }

    const int col0 = bn + nh + l16;
    const int col1 = col0 + 16;
    float bias0 = bias ? bias[col0] : 0.f;
    float bias1 = bias ? bias[col1] : 0.f;

    f32x4 accs[2][2] = {{acc00, acc01}, {acc10, acc11}};
    #pragma unroll
    for (int mt = 0; mt < 2; ++mt) {
        #pragma unroll
        for (int r = 0; r < 4; ++r) {
            int row = bm + mh + mt * 16 + quad * 4 + r;
            size_t rowoff = (size_t)row * ldc;
            float v0 = accs[mt][0][r] + bias0;
            float v1 = accs[mt][1][r] + bias1;
            if (EPI == 1) { v0 = __expf(2.f * v0); v1 = __expf(2.f * v1); }
            if (EPI == 3) { v0 += partial[rowoff + col0]; v1 += partial[rowoff + col1]; }
            if (EPI == 2) {
                ushort_t* C = (ushort_t*)Cv;
                C[rowoff + col0] = f2bf(v0);
                C[rowoff + col1] = f2bf(v1);
            } else {
                float* C = (float*)Cv;
                C[rowoff + col0] = v0;
                C[rowoff + col1] = v1;
            }
        }
    }
}

// ---------------------------------------------------------------------------
// K0: fp32 -> bf16 pre-convert. 2048 elems/block (256 thr x 8).
// [0,128) inp | [128,640) ctx | [640,768) Wq | [768,896) Wc | [896,1152) Wout
// ---------------------------------------------------------------------------
__global__ __launch_bounds__(256) void cvt_bf16(
    const float* __restrict__ inp, const float* __restrict__ ctx,
    const float* __restrict__ Wq, const float* __restrict__ Wc,
    const float* __restrict__ Wout,
    ushort_t* __restrict__ inpb, ushort_t* __restrict__ ctxb,
    ushort_t* __restrict__ Wqb, ushort_t* __restrict__ Wcb,
    ushort_t* __restrict__ Woutb)
{
    const int bid = blockIdx.x;
    const float* src; ushort_t* dst; int base;
    if (bid < 128)      { src = inp;  dst = inpb;  base = bid; }
    else if (bid < 640) { src = ctx;  dst = ctxb;  base = bid - 128; }
    else if (bid < 768) { src = Wq;   dst = Wqb;   base = bid - 640; }
    else if (bid < 896) { src = Wc;   dst = Wcb;   base = bid - 768; }
    else                { src = Wout; dst = Woutb; base = bid - 896; }
    const size_t off = (size_t)base * 2048 + (size_t)threadIdx.x * 8;
    const float4* s = (const float4*)(src + off);
    float4 a = s[0], b = s[1];
    int4 r;
    r.x = bf2x(a.x, a.y); r.y = bf2x(a.z, a.w);
    r.z = bf2x(b.x, b.y); r.w = bf2x(b.z, b.w);
    *(int4*)(dst + off) = r;
}

// ---------------------------------------------------------------------------
// K1: fused front (640 GEMM blocks), all operands bf16
// [0,64)    Ew = exp(2*(inp@Wq^T + bq))
// [64,320)  Eu = exp(2*(ctx@Wc^T))
// [320,576) GT[b][n,s] = sum_d WL[n,d]*ctx[b][s,d]  (bf16)
// [576,640) Y0 = inp@WR^T + bout
// ---------------------------------------------------------------------------
__global__ __launch_bounds__(256) void fused_front(
    const ushort_t* __restrict__ inpb, const ushort_t* __restrict__ ctxb,
    const ushort_t* __restrict__ Wqb, const float* __restrict__ bq,
    const ushort_t* __restrict__ Wcb, const ushort_t* __restrict__ Woutb,
    const float* __restrict__ bout,
    float* __restrict__ Ew, float* __restrict__ Eu, float* __restrict__ Y0,
    ushort_t* __restrict__ GT)
{
    __shared__ ushort_t As[2 * 4608];
    __shared__ ushort_t Ws[2 * 4608];
    const int bid = blockIdx.x;

    if (bid < 64) {
        gemm_body<true, true, 1>(As, Ws, inpb, Wqb, bq, nullptr, Ew,
                                 512, 512, 512, (bid & 7) * 64, (bid >> 3) * 64);
    } else if (bid < 320) {
        int i = bid - 64;
        gemm_body<true, true, 1>(As, Ws, ctxb, Wcb, nullptr, nullptr, Eu,
                                 512, 512, 512, (i & 31) * 64, (i >> 5) * 64);
    } else if (bid < 576) {
        int i = bid - 320;
        int b = i >> 6, j = i & 63;
        gemm_body<true, true, 2>(As, Ws, Woutb, ctxb + (size_t)b * 262144, nullptr,
                                 nullptr, GT + (size_t)b * 262144,
                                 1024, 512, 512, (j & 7) * 64, (j >> 3) * 64);
    } else {
        int i = bid - 576;
        gemm_body<true, true, 0>(As, Ws, inpb, Woutb + 512, bout, nullptr, Y0,
                                 512, 1024, 512, (i & 7) * 64, (i >> 3) * 64);
    }
}

// ---------------------------------------------------------------------------
// K2: E[b,t,s] = exp(V - 2*sum_d v[d]/(1 + Ew[b,t,d]*Eu[b,s,d])),  V = sum v[d]
// Main loop: k across lanes, paired rcp (1 rcp / 2 d-elems).
// Tail: multi-value halving butterfly (32 shuffles); maxless exp. [R13 verbatim]
// ---------------------------------------------------------------------------
__global__ __launch_bounds__(256) void align_kernel(
    const float* __restrict__ Ew, const float* __restrict__ Eu,
    const float* __restrict__ v, float* __restrict__ out)
{
    const int lane = threadIdx.x & 63, wave = threadIdx.x >> 6;
    const int b = blockIdx.z;
    const int t0 = blockIdx.y * 16 + wave * 4;
    const int s0 = blockIdx.x * 8;

    const float* wp = Ew + (((size_t)(b * 128 + t0)) << 9);
    const float* up = Eu + (((size_t)(b * 512 + s0)) << 9);

    float acc[4][8];
    #pragma unroll
    for (int i = 0; i < 4; ++i)
        #pragma unroll
        for (int j = 0; j < 8; ++j) acc[i][j] = 0.f;
    float vsum = 0.f;

    for (int k0 = 0; k0 < 512; k0 += 128) {
        float va = v[k0 + lane];
        float vb = v[k0 + 64 + lane];
        vsum += va + vb;
        float wa[4], wb[4];
        #pragma unroll
        for (int i = 0; i < 4; ++i) {
            wa[i] = wp[i * 512 + k0 + lane];
            wb[i] = wp[i * 512 + k0 + 64 + lane];
        }
        #pragma unroll
        for (int j = 0; j < 8; ++j) {
            const float* u = up + ((size_t)j << 9) + k0 + lane;
            float ua = u[0];
            float ub = u[64];
            #pragma unroll
            for (int i = 0; i < 4; ++i) {
                float A = fmaf(wa[i], ua, 1.f);
                float B = fmaf(wb[i], ub, 1.f);
                float num = fmaf(va, B, vb * A);
                float r = __builtin_amdgcn_rcpf(A * B);
                acc[i][j] = fmaf(num, r, acc[i][j]);
            }
        }
    }

    float V = vsum;
    #pragma unroll
    for (int off = 32; off; off >>= 1) V += __shfl_xor(V, off, 64);

    float x16[16];
    {
        const bool hb = lane & 1;
        #pragma unroll
        for (int i = 0; i < 4; ++i)
            #pragma unroll
            for (int m = 0; m < 4; ++m) {
                float keep = hb ? acc[i][2 * m + 1] : acc[i][2 * m];
                float send = hb ? acc[i][2 * m]     : acc[i][2 * m + 1];
                x16[i * 4 + m] = keep + __shfl_xor(send, 1, 64);
            }
    }
    float x8[8];
    {
        const bool hb = lane & 2;
        #pragma unroll
        for (int m = 0; m < 8; ++m) {
            float keep = hb ? x16[2 * m + 1] : x16[2 * m];
            float send = hb ? x16[2 * m]     : x16[2 * m + 1];
            x8[m] = keep + __shfl_xor(send, 2, 64);
        }
    }
    float x4[4];
    {
        const bool hb = lane & 4;
        #pragma unroll
        for (int m = 0; m < 4; ++m) {
            float keep = hb ? x8[2 * m + 1] : x8[2 * m];
            float send = hb ? x8[2 * m]     : x8[2 * m + 1];
            x4[m] = keep + __shfl_xor(send, 4, 64);
        }
    }
    float x2[2];
    {
        const bool hb = lane & 8;
        #pragma unroll
        for (int m = 0; m < 2; ++m) {
            float keep = hb ? x4[2 * m + 1] : x4[2 * m];
            float send = hb ? x4[2 * m]     : x4[2 * m + 1];
            x2[m] = keep + __shfl_xor(send, 8, 64);
        }
    }
    float x1;
    {
        const bool hb = lane & 16;
        float keep = hb ? x2[1] : x2[0];
        float send = hb ? x2[0] : x2[1];
        x1 = keep + __shfl_xor(send, 16, 64);
    }
    x1 += __shfl_xor(x1, 32, 64);

    const int oi = (lane >> 3) & 3;
    const int oj = lane & 7;
    float e = __expf(fmaf(-2.f, x1, V));
    if (lane < 32) {
        out[(((size_t)(b * 128 + t0 + oi)) << 9) + s0 + oj] = e;
    }
}

// ---------------------------------------------------------------------------
// K3: maxless normalize over rows of 512. Reads E=exp(S), writes fp32 alignv
// (=E/rowsum) + bf16 P.  [R13 verbatim]
// ---------------------------------------------------------------------------
__global__ __launch_bounds__(256) void normalize_512(
    const float* __restrict__ E, float* __restrict__ alignv,
    ushort_t* __restrict__ pbf)
{
    const int row = blockIdx.x;
    const float* p = E + ((size_t)row << 9);
    float* a = alignv + ((size_t)row << 9);
    ushort_t* q = pbf + ((size_t)row << 9);
    const int tid = threadIdx.x;
    float e0 = p[tid];
    float e1 = p[tid + 256];

    float s = e0 + e1;
    #pragma unroll
    for (int off = 32; off > 0; off >>= 1)
        s += __shfl_xor(s, off, 64);
    __shared__ float reds[4];
    const int wave = tid >> 6;
    if ((tid & 63) == 0) reds[wave] = s;
    __syncthreads();
    s = (reds[0] + reds[1]) + (reds[2] + reds[3]);
    float r = 1.0f / s;
    float p0 = e0 * r, p1 = e1 * r;
    a[tid] = p0;
    a[tid + 256] = p1;
    q[tid] = f2bf(p0);
    q[tid + 256] = f2bf(p1);
}

// ---------------------------------------------------------------------------
// K4: attn = P_bf @ GT^T + Y0. Per-batch M=128, N=512, K=512. Grid (2,8,4).
// ---------------------------------------------------------------------------
__global__ __launch_bounds__(256) void gemm_att(
    const ushort_t* __restrict__ P, const ushort_t* __restrict__ GT,
    const float* __restrict__ Y0, float* __restrict__ attn)
{
    __shared__ ushort_t As[2 * 4608];
    __shared__ ushort_t Ws[2 * 4608];
    const int b = blockIdx.z;
    gemm_body<true, true, 3>(As, Ws,
                             P + (size_t)b * 65536, GT + (size_t)b * 262144,
                             nullptr, Y0 + (size_t)b * 65536,
                             attn + (size_t)b * 65536,
                             512, 512, 512, blockIdx.x * 64, blockIdx.y * 64);
}

// ---------------------------------------------------------------------------
extern "C" void kernel_launch(void* const* d_in, const int* in_sizes, int n_in,
                              void* d_out, int out_size, void* d_ws, size_t ws_size,
                              hipStream_t stream)
{
    const float* inp  = (const float*)d_in[0];   // (4,128,512)
    const float* ctx  = (const float*)d_in[1];   // (4,512,512)
    const float* Wq   = (const float*)d_in[2];   // (512,512)
    const float* bq   = (const float*)d_in[3];   // (512)
    const float* Wc   = (const float*)d_in[4];   // (512,512)
    const float* v    = (const float*)d_in[5];   // (512)
    const float* Wout = (const float*)d_in[6];   // (512,1024)
    const float* bout = (const float*)d_in[7];   // (512)

    float* out    = (float*)d_out;
    float* attn   = out;              // 262144 floats
    float* alignv = out + 262144;     // 262144 floats

    float* ws = (float*)d_ws;
    float* Ew   = ws;                             // 262144 f
    float* Eu   = ws + 262144;                    // 1048576 f
    float* Y0   = ws + 1310720;                   // 262144 f
    float* E    = ws + 1572864;                   // 262144 f (exp of raw scores)
    ushort_t* GT   = (ushort_t*)(ws + 1835008);   // 1048576 u16 (= 524288 f)
    ushort_t* P_bf = (ushort_t*)(ws + 2359296);   // 262144 u16 (= 131072 f)
    ushort_t* inpb  = (ushort_t*)(ws + 2490368);  // 262144 u16
    ushort_t* ctxb  = (ushort_t*)(ws + 2621440);  // 1048576 u16
    ushort_t* Wqb   = (ushort_t*)(ws + 3145728);  // 262144 u16
    ushort_t* Wcb   = (ushort_t*)(ws + 3276800);  // 262144 u16
    ushort_t* Woutb = (ushort_t*)(ws + 3407872);  // 524288 u16

    cvt_bf16<<<dim3(1152), 256, 0, stream>>>(inp, ctx, Wq, Wc, Wout,
                                             inpb, ctxb, Wqb, Wcb, Woutb);
    fused_front<<<dim3(640), 256, 0, stream>>>(inpb, ctxb, Wqb, bq, Wcb, Woutb,
                                               bout, Ew, Eu, Y0, GT);
    align_kernel<<<dim3(64, 8, 4), 256, 0, stream>>>(Ew, Eu, v, E);
    normalize_512<<<dim3(512), 256, 0, stream>>>(E, alignv, P_bf);
    gemm_att<<<dim3(2, 8, 4), 256, 0, stream>>>(P_bf, GT, Y0, attn);
}